// Round 1
// baseline (621.660 us; speedup 1.0000x reference)
//
#include <hip/hip_runtime.h>
#include <hip/hip_bf16.h>
#include <math.h>

// ---------- types ----------
typedef __bf16 bf16x8 __attribute__((ext_vector_type(8)));
typedef __bf16 bf16x4 __attribute__((ext_vector_type(4)));
typedef float  f32x4  __attribute__((ext_vector_type(4)));
typedef unsigned int u32;

#define S_LEN 2048
#define HID   4096
#define NH    32
#define NKV   8
#define HD    128

// async global->LDS 16B: per-lane global addr, LDS dest = wave-uniform base + lane*16
__device__ inline void gld_lds16(const __bf16* g, __bf16* l) {
  __builtin_amdgcn_global_load_lds((const __attribute__((address_space(1))) u32*)g,
                                   (__attribute__((address_space(3))) u32*)l,
                                   16, 0, 0);
}

// ---------- fp32 -> bf16 cast (vectorized) ----------
__global__ void cast_bf16(const float* __restrict__ in, __bf16* __restrict__ out, int n4) {
  int i = blockIdx.x * blockDim.x + threadIdx.x;
  if (i < n4) {
    float4 v = ((const float4*)in)[i];
    bf16x4 o;
    o[0] = (__bf16)v.x; o[1] = (__bf16)v.y; o[2] = (__bf16)v.z; o[3] = (__bf16)v.w;
    ((bf16x4*)out)[i] = o;
  }
}

// ---------- [R][C] (row stride ldi) -> bf16 [C][R] (row stride ldo) ----------
template <typename T>
__global__ void transpose_cast(const T* __restrict__ in, __bf16* __restrict__ out,
                               int ldi, int ldo) {
  __shared__ float tile[32][33];
  const int c0 = blockIdx.x * 32, r0 = blockIdx.y * 32;
  const int tx = threadIdx.x, ty = threadIdx.y;
  for (int j = 0; j < 32; j += 8)
    tile[ty + j][tx] = (float)in[(size_t)(r0 + ty + j) * ldi + c0 + tx];
  __syncthreads();
  for (int j = 0; j < 32; j += 8)
    out[(size_t)(c0 + ty + j) * ldo + r0 + tx] = (__bf16)tile[tx][ty + j];
}

__global__ void concat_bias(const float* __restrict__ bk, const float* __restrict__ bv,
                            float* __restrict__ out) {
  int i = blockIdx.x * blockDim.x + threadIdx.x;
  if (i < 2048) out[i] = (i < 1024) ? bk[i] : bv[i - 1024];
}

// ---------- GEMM: C[M][N] = A[M][K]bf16 @ Bt[N][K]bf16^T + bias[N] ----------
// 128x128 tile, BK=64 (half the barrier drains of BK=32), 4 waves each 64x64.
// Staging chunk c (0..1023): row=c>>3, kc=((c&7)+row)&7 (rotation keeps 8-lane/128B
// global coalescing AND bank-balanced ds_read_b128 fragment reads). LDS linear in c.
template <typename CT>
__global__ __launch_bounds__(256) void gemm_bt(const __bf16* __restrict__ A,
                                               const __bf16* __restrict__ Bt,
                                               const float* __restrict__ bias,
                                               CT* __restrict__ C,
                                               int M, int N, int K) {
  __shared__ __bf16 As[128 * 64];
  __shared__ __bf16 Bs[128 * 64];
  const int tid  = threadIdx.x;
  const int lane = tid & 63;
  const int lrow = lane & 15, quad = lane >> 4;
  const int wave = tid >> 6;
  const int wm = (wave & 1) * 64, wn = (wave >> 1) * 64;
  const int m0 = blockIdx.y * 128, n0 = blockIdx.x * 128;

  f32x4 acc[4][4] = {};

  // staging: 4 chunks per thread per matrix
  const __bf16* aP[4];
  const __bf16* bP[4];
  __bf16* aL[4];
  __bf16* bL[4];
#pragma unroll
  for (int s = 0; s < 4; s++) {
    const int c = tid + 256 * s;
    const int row = c >> 3;
    const int kc = ((c & 7) + row) & 7;
    aP[s] = A + (size_t)(m0 + row) * K + kc * 8;
    bP[s] = Bt + (size_t)(n0 + row) * K + kc * 8;
    aL[s] = As + c * 8;
    bL[s] = Bs + c * 8;
  }

  // fragment LDS element offsets (loop-invariant): chunk = r*8 + ((kc - r)&7)
  int offA[2][4], offB[2][4];
#pragma unroll
  for (int h = 0; h < 2; h++)
#pragma unroll
    for (int t = 0; t < 4; t++) {
      const int ra = wm + t * 16 + lrow;
      const int rb = wn + t * 16 + lrow;
      offA[h][t] = (ra * 8 + ((h * 4 + quad - ra) & 7)) * 8;
      offB[h][t] = (rb * 8 + ((h * 4 + quad - rb) & 7)) * 8;
    }

  for (int k0 = 0; k0 < K; k0 += 64) {
    __syncthreads();
#pragma unroll
    for (int s = 0; s < 4; s++) {
      gld_lds16(aP[s] + k0, aL[s]);
      gld_lds16(bP[s] + k0, bL[s]);
    }
    __syncthreads();

#pragma unroll
    for (int h = 0; h < 2; h++) {
      bf16x8 af[4], bfr[4];
#pragma unroll
      for (int t = 0; t < 4; t++) {
        af[t]  = *(const bf16x8*)(As + offA[h][t]);
        bfr[t] = *(const bf16x8*)(Bs + offB[h][t]);
      }
#pragma unroll
      for (int i = 0; i < 4; i++)
#pragma unroll
        for (int j = 0; j < 4; j++)
          acc[i][j] = __builtin_amdgcn_mfma_f32_16x16x32_bf16(af[i], bfr[j], acc[i][j], 0, 0, 0);
    }
  }

#pragma unroll
  for (int i = 0; i < 4; i++) {
    const int row = m0 + wm + i * 16 + quad * 4;
#pragma unroll
    for (int j = 0; j < 4; j++) {
      const int col = n0 + wn + j * 16 + lrow;
      const float b = bias[col];
#pragma unroll
      for (int r = 0; r < 4; r++)
        C[(size_t)(row + r) * N + col] = (CT)(acc[i][j][r] + b);
    }
  }
}

// ---------- RoPE in-place on bf16: Q [S][4096], KV [S][2048] (K = cols 0..1023) ----------
__global__ void rope_inplace(__bf16* __restrict__ Q, __bf16* __restrict__ KV,
                             const int* __restrict__ pos_ids) {
  const int s = blockIdx.y;
  const int t = blockIdx.x * blockDim.x + threadIdx.x;  // 0..2559
  const int h = t >> 6, j = t & 63;
  const float pos = (float)pos_ids[s];
  const float inv_freq = __builtin_exp2f((float)j * -0.2076205059304601f);
  const float ang = pos * inv_freq;
  float sn, cs;
  sincosf(ang, &sn, &cs);
  if (h < NH) {
    __bf16* p = Q + (size_t)s * HID + h * HD + j;
    const float x0 = (float)p[0], x1 = (float)p[64];
    p[0]  = (__bf16)(x0 * cs - x1 * sn);
    p[64] = (__bf16)(x1 * cs + x0 * sn);
  } else {
    const int hk = h - NH;
    __bf16* p = KV + (size_t)s * 2048 + hk * HD + j;
    const float x0 = (float)p[0], x1 = (float)p[64];
    p[0]  = (__bf16)(x0 * cs - x1 * sn);
    p[64] = (__bf16)(x1 * cs + x0 * sn);
  }
}

// ---------- flash attention v5 ----------
// LDS-traffic-optimized: 2 waves x 64 q-rows (4 m-tiles) per 128-row block.
// K/V fragment LDS reads amortize over 2x the MFMA work vs v4 (32 rows/wave).
//  K chunk c (0..511): key=c>>4, cb=((c&15)+key)&15  -> 16 lanes cover one 256B K-row.
//  V chunk c (0..511): d=c>>2,   cb=((c&3)-(d>>1))&3 -> read rot (quad+(d>>1))&3 makes
//    chunk%8 cover all 8 bank-groups twice per 16-lane phase (2-way = free; old
//    (quad-d)&3 rotation was 4-way). No online max (scores bounded); row-sum via MFMA
//    vs ones. Wave-uniform causal skips: dead tiles (kb>=Tw+64) skipped entirely,
//    fully-valid tiles (kb<Tw+m*16-31+..) take a mask-free exp2 path.
__global__ __launch_bounds__(128, 1) void flash_attn(const __bf16* __restrict__ Qb,
                                                     const __bf16* __restrict__ Kb,
                                                     const __bf16* __restrict__ Vt,
                                                     __bf16* __restrict__ attn, int ldk) {
  __shared__ __bf16 Ks[2][32 * 128];
  __shared__ __bf16 Vs[2][128 * 32];
  __shared__ __bf16 Plds[2][4][16][40];
  const int tid  = threadIdx.x;
  const int wave = tid >> 6;  // 0..1
  const int lane = tid & 63;
  const int lrow = lane & 15, quad = lane >> 4;

  const int c = blockIdx.x & 255, p = blockIdx.x >> 8;
  const int h = c >> 3;
  const int xh = c & 7;
  const int xx = p ? xh : 15 - xh;
  const int bq0 = xx * 128;
  const int kvh = h >> 2;
  const int Tw = bq0 + wave * 64;   // this wave's 64 q-rows: Tw .. Tw+63
  const int kend = bq0 + 128;

  // staging chunk decode (4 K-chunks + 4 V-chunks per thread)
  const __bf16* kg[4];
  const __bf16* vg[4];
  int kL[4], vL[4];
#pragma unroll
  for (int s = 0; s < 4; s++) {
    const int ck = tid + 128 * s;
    const int key = ck >> 4, kcb = ((ck & 15) + key) & 15;
    kg[s] = Kb + (size_t)key * ldk + kvh * HD + kcb * 8;
    kL[s] = ck * 8;
    const int d = ck >> 2, vcb = ((ck & 3) - (d >> 1)) & 3;
    vg[s] = Vt + (size_t)(kvh * HD + d) * S_LEN + vcb * 8;
    vL[s] = ck * 8;
  }

  // fragment offsets (loop-invariant)
  int offK0[4], offK1[4], offV[8];
#pragma unroll
  for (int kc = 0; kc < 4; kc++) {
    const int rot = (kc * 4 + quad - lrow) & 15;
    offK0[kc] = (lrow * 16 + rot) * 8;
    offK1[kc] = ((lrow + 16) * 16 + rot) * 8;
  }
#pragma unroll
  for (int dt = 0; dt < 8; dt++) {
    const int d = dt * 16 + lrow;
    offV[dt] = (d * 4 + ((quad + (d >> 1)) & 3)) * 8;
  }

  // Q fragments (held in regs for whole kernel): 4 m-tiles of 16 rows
  bf16x8 qf[4][4];
#pragma unroll
  for (int m = 0; m < 4; m++) {
    const __bf16* qbase = Qb + (size_t)(Tw + m * 16 + lrow) * HID + h * HD + quad * 8;
#pragma unroll
    for (int kc = 0; kc < 4; kc++) qf[m][kc] = *(const bf16x8*)(qbase + kc * 32);
  }

  f32x4 o[4][8] = {};
  f32x4 lac[4] = {};
  bf16x8 ones;
#pragma unroll
  for (int j = 0; j < 8; j++) ones[j] = (__bf16)1.0f;

  const float cs = 0.08838834764831845f * 1.44269504088896f;  // 1/sqrt(128)*log2(e)

  // preload tile kb=0 into buffer 0
#pragma unroll
  for (int s = 0; s < 4; s++) {
    gld_lds16(kg[s], &Ks[0][0] + kL[s]);
    gld_lds16(vg[s], &Vs[0][0] + vL[s]);
  }

  int cur = 0;
  for (int kb = 0; kb < kend; kb += 32) {
    __syncthreads();  // drains outstanding gld_lds (vmcnt) then barrier
    if (kb + 32 < kend) {
      const int nxt = cur ^ 1;
#pragma unroll
      for (int s = 0; s < 4; s++) {
        gld_lds16(kg[s] + (size_t)(kb + 32) * ldk, &Ks[nxt][0] + kL[s]);
        gld_lds16(vg[s] + (kb + 32), &Vs[nxt][0] + vL[s]);
      }
    }

    // wave-uniform: skip tiles entirely above the causal diagonal for this wave
    if (kb < Tw + 64) {
      // K fragments from LDS (shared by all 4 m-tiles)
      bf16x8 kf0[4], kf1[4];
#pragma unroll
      for (int kc = 0; kc < 4; kc++) {
        kf0[kc] = *(const bf16x8*)(&Ks[cur][offK0[kc]]);
        kf1[kc] = *(const bf16x8*)(&Ks[cur][offK1[kc]]);
      }
      f32x4 sc[4][2] = {};
#pragma unroll
      for (int kc = 0; kc < 4; kc++) {
#pragma unroll
        for (int m = 0; m < 4; m++) {
          sc[m][0] = __builtin_amdgcn_mfma_f32_16x16x32_bf16(qf[m][kc], kf0[kc], sc[m][0], 0, 0, 0);
          sc[m][1] = __builtin_amdgcn_mfma_f32_16x16x32_bf16(qf[m][kc], kf1[kc], sc[m][1], 0, 0, 0);
        }
      }
      // exp2 (no max-sub) + causal mask, C-layout -> LDS
#pragma unroll
      for (int m = 0; m < 4; m++) {
        const int rmin = Tw + m * 16;  // min row of this m-tile
        if (kb + 31 <= rmin) {
          // fully-valid tile: mask-free
#pragma unroll
          for (int n = 0; n < 2; n++)
#pragma unroll
            for (int r = 0; r < 4; r++)
              Plds[wave][m][quad * 4 + r][n * 16 + lrow] =
                  (__bf16)__builtin_exp2f(sc[m][n][r] * cs);
        } else {
          const int rb = rmin + quad * 4;
#pragma unroll
          for (int n = 0; n < 2; n++) {
            const int col = kb + n * 16 + lrow;
#pragma unroll
            for (int r = 0; r < 4; r++) {
              const float pv = (col <= rb + r) ? __builtin_exp2f(sc[m][n][r] * cs) : 0.0f;
              Plds[wave][m][quad * 4 + r][n * 16 + lrow] = (__bf16)pv;
            }
          }
        }
      }
      // A-layout fragments (per-wave slice; same-wave DS ordering, no barrier)
      bf16x8 pf[4];
#pragma unroll
      for (int m = 0; m < 4; m++) pf[m] = *(const bf16x8*)(&Plds[wave][m][lrow][quad * 8]);
#pragma unroll
      for (int dt = 0; dt < 8; dt++) {
        bf16x8 vf = *(const bf16x8*)(&Vs[cur][offV[dt]]);
#pragma unroll
        for (int m = 0; m < 4; m++)
          o[m][dt] = __builtin_amdgcn_mfma_f32_16x16x32_bf16(pf[m], vf, o[m][dt], 0, 0, 0);
      }
#pragma unroll
      for (int m = 0; m < 4; m++)
        lac[m] = __builtin_amdgcn_mfma_f32_16x16x32_bf16(pf[m], ones, lac[m], 0, 0, 0);
    }
    cur ^= 1;
  }

#pragma unroll
  for (int m = 0; m < 4; m++) {
    const int Tm = Tw + m * 16;
#pragma unroll
    for (int r = 0; r < 4; r++) {
      const float inv_l = 1.0f / lac[m][r];
      const size_t rowoff = (size_t)(Tm + quad * 4 + r) * HID + h * HD;
#pragma unroll
      for (int dt = 0; dt < 8; dt++)
        attn[rowoff + dt * 16 + lrow] = (__bf16)(o[m][dt][r] * inv_l);
    }
  }
}

// ---------- launch ----------
extern "C" void kernel_launch(void* const* d_in, const int* in_sizes, int n_in,
                              void* d_out, int out_size, void* d_ws, size_t ws_size,
                              hipStream_t stream) {
  const float* hs = (const float*)d_in[0];
  const int* pos = (const int*)d_in[2];
  const float* Wq = (const float*)d_in[3];
  const float* bq = (const float*)d_in[4];
  const float* Wk = (const float*)d_in[5];
  const float* bk = (const float*)d_in[6];
  const float* Wv = (const float*)d_in[7];
  const float* bv = (const float*)d_in[8];
  const float* Wo = (const float*)d_in[9];
  const float* bo = (const float*)d_in[10];
  float* out = (float*)d_out;
  char* ws = (char*)d_ws;
  char* oc = (char*)d_out;

  // ws layout (48 MB total):
  __bf16* bHS   = (__bf16*)(ws + 0);                   // 16 MB; reused as bAttn
  __bf16* bWT   = (__bf16*)(ws + ((size_t)16 << 20));  // 32 MB transposed weights
  __bf16* bAttn = bHS;
  // d_out scratch (28 MB of its 32 MB; final GEMM overwrites everything):
  __bf16* bQ   = (__bf16*)(oc + 0);                    // 16 MB [2048][4096]
  __bf16* bKV  = (__bf16*)(oc + ((size_t)16 << 20));   // 8 MB  [2048][2048] = K|V
  __bf16* bVt  = (__bf16*)(oc + ((size_t)24 << 20));   // 4 MB  [1024][2048]
  float*  bKVb = (float*)(oc + ((size_t)28 << 20));    // 8 KB concat bias

  dim3 tb(32, 8);

  // 1. hidden -> bf16
  cast_bf16<<<8192, 256, 0, stream>>>(hs, bHS, (S_LEN * HID) / 4);
  // 2. Wq^T ; Q = hs @ Wq + bq  (bf16 out into d_out scratch)
  transpose_cast<float><<<dim3(128, 128), tb, 0, stream>>>(Wq, bWT, 4096, 4096);
  gemm_bt<__bf16><<<dim3(32, 16), 256, 0, stream>>>(bHS, bWT, bq, bQ, 2048, 4096, 4096);
  // 3. [Wk|Wv]^T fused ; KV = hs @ [Wk|Wv] + [bk|bv]
  transpose_cast<float><<<dim3(32, 128), tb, 0, stream>>>(Wk, bWT, 1024, 4096);
  transpose_cast<float><<<dim3(32, 128), tb, 0, stream>>>(Wv, bWT + (size_t)1024 * 4096, 1024, 4096);
  concat_bias<<<8, 256, 0, stream>>>(bk, bv, bKVb);
  gemm_bt<__bf16><<<dim3(16, 16), 256, 0, stream>>>(bHS, bWT, bKVb, bKV, 2048, 2048, 4096);
  // 4. RoPE in-place on bQ and K-part of bKV ; V -> V^T
  rope_inplace<<<dim3(10, 2048), 256, 0, stream>>>(bQ, bKV, pos);
  transpose_cast<__bf16><<<dim3(32, 64), tb, 0, stream>>>(bKV + 1024, bVt, 2048, 2048);
  // 5. flash attention -> bAttn (reuses bHS region)
  flash_attn<<<512, 128, 0, stream>>>(bQ, bKV, bVt, bAttn, 2048);
  // 6. Wo^T ; out = attn @ Wo + bo (fp32, overwrites all d_out scratch)
  transpose_cast<float><<<dim3(128, 128), tb, 0, stream>>>(Wo, bWT, 4096, 4096);
  gemm_bt<float><<<dim3(32, 16), 256, 0, stream>>>(bAttn, bWT, bo, out, 2048, 4096, 4096);
}

// Round 3
// 575.587 us; speedup vs baseline: 1.0800x; 1.0800x over previous
//
#include <hip/hip_runtime.h>
#include <hip/hip_bf16.h>
#include <math.h>

// ---------- types ----------
typedef __bf16 bf16x8 __attribute__((ext_vector_type(8)));
typedef __bf16 bf16x4 __attribute__((ext_vector_type(4)));
typedef float  f32x4  __attribute__((ext_vector_type(4)));
typedef unsigned int u32;

#define S_LEN 2048
#define HID   4096
#define NH    32
#define NKV   8
#define HD    128

// async global->LDS 16B: per-lane global addr, LDS dest = wave-uniform base + lane*16
__device__ inline void gld_lds16(const __bf16* g, __bf16* l) {
  __builtin_amdgcn_global_load_lds((const __attribute__((address_space(1))) u32*)g,
                                   (__attribute__((address_space(3))) u32*)l,
                                   16, 0, 0);
}

// ---------- fp32 -> bf16 cast (vectorized) ----------
__global__ void cast_bf16(const float* __restrict__ in, __bf16* __restrict__ out, int n4) {
  int i = blockIdx.x * blockDim.x + threadIdx.x;
  if (i < n4) {
    float4 v = ((const float4*)in)[i];
    bf16x4 o;
    o[0] = (__bf16)v.x; o[1] = (__bf16)v.y; o[2] = (__bf16)v.z; o[3] = (__bf16)v.w;
    ((bf16x4*)out)[i] = o;
  }
}

// ---------- [R][C] (row stride ldi) -> bf16 [C][R] (row stride ldo) ----------
template <typename T>
__global__ void transpose_cast(const T* __restrict__ in, __bf16* __restrict__ out,
                               int ldi, int ldo) {
  __shared__ float tile[32][33];
  const int c0 = blockIdx.x * 32, r0 = blockIdx.y * 32;
  const int tx = threadIdx.x, ty = threadIdx.y;
  for (int j = 0; j < 32; j += 8)
    tile[ty + j][tx] = (float)in[(size_t)(r0 + ty + j) * ldi + c0 + tx];
  __syncthreads();
  for (int j = 0; j < 32; j += 8)
    out[(size_t)(c0 + ty + j) * ldo + r0 + tx] = (__bf16)tile[tx][ty + j];
}

__global__ void concat_bias(const float* __restrict__ bk, const float* __restrict__ bv,
                            float* __restrict__ out) {
  int i = blockIdx.x * blockDim.x + threadIdx.x;
  if (i < 2048) out[i] = (i < 1024) ? bk[i] : bv[i - 1024];
}

// ---------- GEMM: C[M][N] = A[M][K]bf16 @ Bt[N][K]bf16^T + bias[N] ----------
// 128x128 tile, BK=64, 4 waves each 64x64. Staging chunk c (0..1023): row=c>>3,
// kc=((c&7)+row)&7 (rotation keeps 8-lane/128B global coalescing AND bank-balanced
// ds_read_b128 fragment reads). LDS linear in c.
template <typename CT>
__global__ __launch_bounds__(256) void gemm_bt(const __bf16* __restrict__ A,
                                               const __bf16* __restrict__ Bt,
                                               const float* __restrict__ bias,
                                               CT* __restrict__ C,
                                               int M, int N, int K) {
  __shared__ __bf16 As[128 * 64];
  __shared__ __bf16 Bs[128 * 64];
  const int tid  = threadIdx.x;
  const int lane = tid & 63;
  const int lrow = lane & 15, quad = lane >> 4;
  const int wave = tid >> 6;
  const int wm = (wave & 1) * 64, wn = (wave >> 1) * 64;
  const int m0 = blockIdx.y * 128, n0 = blockIdx.x * 128;

  f32x4 acc[4][4] = {};

  // staging: 4 chunks per thread per matrix
  const __bf16* aP[4];
  const __bf16* bP[4];
  __bf16* aL[4];
  __bf16* bL[4];
#pragma unroll
  for (int s = 0; s < 4; s++) {
    const int c = tid + 256 * s;
    const int row = c >> 3;
    const int kc = ((c & 7) + row) & 7;
    aP[s] = A + (size_t)(m0 + row) * K + kc * 8;
    bP[s] = Bt + (size_t)(n0 + row) * K + kc * 8;
    aL[s] = As + c * 8;
    bL[s] = Bs + c * 8;
  }

  // fragment LDS element offsets (loop-invariant): chunk = r*8 + ((kc - r)&7)
  int offA[2][4], offB[2][4];
#pragma unroll
  for (int h = 0; h < 2; h++)
#pragma unroll
    for (int t = 0; t < 4; t++) {
      const int ra = wm + t * 16 + lrow;
      const int rb = wn + t * 16 + lrow;
      offA[h][t] = (ra * 8 + ((h * 4 + quad - ra) & 7)) * 8;
      offB[h][t] = (rb * 8 + ((h * 4 + quad - rb) & 7)) * 8;
    }

  for (int k0 = 0; k0 < K; k0 += 64) {
    __syncthreads();
#pragma unroll
    for (int s = 0; s < 4; s++) {
      gld_lds16(aP[s] + k0, aL[s]);
      gld_lds16(bP[s] + k0, bL[s]);
    }
    __syncthreads();

#pragma unroll
    for (int h = 0; h < 2; h++) {
      bf16x8 af[4], bfr[4];
#pragma unroll
      for (int t = 0; t < 4; t++) {
        af[t]  = *(const bf16x8*)(As + offA[h][t]);
        bfr[t] = *(const bf16x8*)(Bs + offB[h][t]);
      }
#pragma unroll
      for (int i = 0; i < 4; i++)
#pragma unroll
        for (int j = 0; j < 4; j++)
          acc[i][j] = __builtin_amdgcn_mfma_f32_16x16x32_bf16(af[i], bfr[j], acc[i][j], 0, 0, 0);
    }
  }

#pragma unroll
  for (int i = 0; i < 4; i++) {
    const int row = m0 + wm + i * 16 + quad * 4;
#pragma unroll
    for (int j = 0; j < 4; j++) {
      const int col = n0 + wn + j * 16 + lrow;
      const float b = bias[col];
#pragma unroll
      for (int r = 0; r < 4; r++)
        C[(size_t)(row + r) * N + col] = (CT)(acc[i][j][r] + b);
    }
  }
}

// ---------- RoPE in-place on bf16: Q [S][4096], KV [S][2048] (K = cols 0..1023) ----------
__global__ void rope_inplace(__bf16* __restrict__ Q, __bf16* __restrict__ KV,
                             const int* __restrict__ pos_ids) {
  const int s = blockIdx.y;
  const int t = blockIdx.x * blockDim.x + threadIdx.x;  // 0..2559
  const int h = t >> 6, j = t & 63;
  const float pos = (float)pos_ids[s];
  const float inv_freq = __builtin_exp2f((float)j * -0.2076205059304601f);
  const float ang = pos * inv_freq;
  float sn, cs;
  sincosf(ang, &sn, &cs);
  if (h < NH) {
    __bf16* p = Q + (size_t)s * HID + h * HD + j;
    const float x0 = (float)p[0], x1 = (float)p[64];
    p[0]  = (__bf16)(x0 * cs - x1 * sn);
    p[64] = (__bf16)(x1 * cs + x0 * sn);
  } else {
    const int hk = h - NH;
    __bf16* p = KV + (size_t)s * 2048 + hk * HD + j;
    const float x0 = (float)p[0], x1 = (float)p[64];
    p[0]  = (__bf16)(x0 * cs - x1 * sn);
    p[64] = (__bf16)(x1 * cs + x0 * sn);
  }
}

// ---------- flash attention v6 ----------
// v4 structure (256 thr, 4 waves x 32 q-rows = proven 3 blocks/CU, 12 waves/CU)
// + fixed V bank rotation (v5-proven: conflicts 5.0M -> 1.6M):
//     stage: d=c>>2, vcb=((c&3)-(d>>1))&3 ; read rot (quad+(d>>1))&3
//     -> per-16-lane-phase banks 16(lrow&1)+4((quad+(lrow>>1))&3): 2-way = free.
// + wave-uniform causal dead-half skip: m-half dead iff kb > Tm+15 -> skip its
//   QK MFMA, exp2, P round-trip, PV MFMA, lac (saves ~6% MFMA, more VALU).
// + mask-free exp2 fast path for fully-valid tiles (kb+31 <= Tm).
// + s_setprio(1) around MFMA clusters (T5).
// No online max (scores bounded); row-sum via MFMA vs ones.
__global__ __launch_bounds__(256) void flash_attn(const __bf16* __restrict__ Qb,
                                                  const __bf16* __restrict__ Kb,
                                                  const __bf16* __restrict__ Vt,
                                                  __bf16* __restrict__ attn, int ldk) {
  __shared__ __bf16 Ks[2][32 * 128];
  __shared__ __bf16 Vs[2][128 * 32];
  __shared__ __bf16 Plds[4][2][16][40];
  const int tid  = threadIdx.x;
  const int wave = tid >> 6;
  const int lane = tid & 63;
  const int lrow = lane & 15, quad = lane >> 4;

  const int c = blockIdx.x & 255, p = blockIdx.x >> 8;
  const int h = c >> 3;
  const int xh = c & 7;
  const int xx = p ? xh : 15 - xh;
  const int bq0 = xx * 128;
  const int kvh = h >> 2;
  const int T0 = bq0 + wave * 16;
  const int T1 = T0 + 64;
  const int kend = bq0 + 128;

  // staging chunk decode (2 K-chunks + 2 V-chunks per thread)
  const __bf16* kg[2];
  const __bf16* vg[2];
  int kL[2], vL[2];
#pragma unroll
  for (int s = 0; s < 2; s++) {
    const int ck = tid + 256 * s;
    const int key = ck >> 4, kcb = ((ck & 15) + key) & 15;
    kg[s] = Kb + (size_t)key * ldk + kvh * HD + kcb * 8;
    kL[s] = ck * 8;
    const int d = ck >> 2, vcb = ((ck & 3) - (d >> 1)) & 3;
    vg[s] = Vt + (size_t)(kvh * HD + d) * S_LEN + vcb * 8;
    vL[s] = ck * 8;
  }

  // fragment offsets (loop-invariant)
  int offK0[4], offK1[4], offV[8];
#pragma unroll
  for (int kc = 0; kc < 4; kc++) {
    const int rot = (kc * 4 + quad - lrow) & 15;
    offK0[kc] = (lrow * 16 + rot) * 8;
    offK1[kc] = ((lrow + 16) * 16 + rot) * 8;
  }
#pragma unroll
  for (int dt = 0; dt < 8; dt++) {
    const int d = dt * 16 + lrow;
    offV[dt] = (d * 4 + ((quad + (d >> 1)) & 3)) * 8;
  }

  // Q fragments (held in regs for whole kernel)
  bf16x8 qf[2][4];
#pragma unroll
  for (int m = 0; m < 2; m++) {
    const __bf16* qbase = Qb + (size_t)(T0 + m * 64 + lrow) * HID + h * HD + quad * 8;
#pragma unroll
    for (int kc = 0; kc < 4; kc++) qf[m][kc] = *(const bf16x8*)(qbase + kc * 32);
  }

  f32x4 o[2][8] = {};
  f32x4 lac[2] = {};
  bf16x8 ones;
#pragma unroll
  for (int j = 0; j < 8; j++) ones[j] = (__bf16)1.0f;

  const float cs = 0.08838834764831845f * 1.44269504088896f;  // 1/sqrt(128)*log2(e)

  // preload tile kb=0 into buffer 0
#pragma unroll
  for (int s = 0; s < 2; s++) {
    gld_lds16(kg[s], &Ks[0][0] + kL[s]);
    gld_lds16(vg[s], &Vs[0][0] + vL[s]);
  }

  int cur = 0;
  for (int kb = 0; kb < kend; kb += 32) {
    __syncthreads();  // drains outstanding gld_lds (vmcnt) then barrier
    if (kb + 32 < kend) {
      const int nxt = cur ^ 1;
#pragma unroll
      for (int s = 0; s < 2; s++) {
        gld_lds16(kg[s] + (size_t)(kb + 32) * ldk, &Ks[nxt][0] + kL[s]);
        gld_lds16(vg[s] + (kb + 32), &Vs[nxt][0] + vL[s]);
      }
    }

    // wave-uniform causal liveness per m-half (rows Tm..Tm+15; tile live iff kb<=Tm+15)
    const bool live0 = (kb <= T0 + 15);  // live0 implies live1 (T1 > T0)
    const bool live1 = (kb <= T1 + 15);

    if (live1) {
      // K fragments from LDS (shared by both m-tiles)
      bf16x8 kf0[4], kf1[4];
#pragma unroll
      for (int kc = 0; kc < 4; kc++) {
        kf0[kc] = *(const bf16x8*)(&Ks[cur][offK0[kc]]);
        kf1[kc] = *(const bf16x8*)(&Ks[cur][offK1[kc]]);
      }
      f32x4 sc[2][2] = {};
      __builtin_amdgcn_s_setprio(1);
      if (live0) {
#pragma unroll
        for (int kc = 0; kc < 4; kc++) {
          sc[0][0] = __builtin_amdgcn_mfma_f32_16x16x32_bf16(qf[0][kc], kf0[kc], sc[0][0], 0, 0, 0);
          sc[0][1] = __builtin_amdgcn_mfma_f32_16x16x32_bf16(qf[0][kc], kf1[kc], sc[0][1], 0, 0, 0);
          sc[1][0] = __builtin_amdgcn_mfma_f32_16x16x32_bf16(qf[1][kc], kf0[kc], sc[1][0], 0, 0, 0);
          sc[1][1] = __builtin_amdgcn_mfma_f32_16x16x32_bf16(qf[1][kc], kf1[kc], sc[1][1], 0, 0, 0);
        }
      } else {
#pragma unroll
        for (int kc = 0; kc < 4; kc++) {
          sc[1][0] = __builtin_amdgcn_mfma_f32_16x16x32_bf16(qf[1][kc], kf0[kc], sc[1][0], 0, 0, 0);
          sc[1][1] = __builtin_amdgcn_mfma_f32_16x16x32_bf16(qf[1][kc], kf1[kc], sc[1][1], 0, 0, 0);
        }
      }
      __builtin_amdgcn_s_setprio(0);

      // exp2 (no max-sub) + causal mask, C-layout -> LDS (per-m fast/masked paths)
#pragma unroll
      for (int m = 0; m < 2; m++) {
        if (m == 0 && !live0) continue;
        const int Tm = m ? T1 : T0;
        if (kb + 31 <= Tm) {
          // fully-valid tile: mask-free
#pragma unroll
          for (int n = 0; n < 2; n++)
#pragma unroll
            for (int r = 0; r < 4; r++)
              Plds[wave][m][quad * 4 + r][n * 16 + lrow] =
                  (__bf16)__builtin_exp2f(sc[m][n][r] * cs);
        } else {
          const int rb = Tm + quad * 4;
#pragma unroll
          for (int n = 0; n < 2; n++) {
            const int col = kb + n * 16 + lrow;
#pragma unroll
            for (int r = 0; r < 4; r++) {
              const float pv = (col <= rb + r) ? __builtin_exp2f(sc[m][n][r] * cs) : 0.0f;
              Plds[wave][m][quad * 4 + r][n * 16 + lrow] = (__bf16)pv;
            }
          }
        }
      }
      // A-layout fragments (per-wave slice; same-wave DS ordering, no barrier)
      bf16x8 pf1 = *(const bf16x8*)(&Plds[wave][1][lrow][quad * 8]);
      __builtin_amdgcn_s_setprio(1);
      if (live0) {
        bf16x8 pf0 = *(const bf16x8*)(&Plds[wave][0][lrow][quad * 8]);
#pragma unroll
        for (int dt = 0; dt < 8; dt++) {
          bf16x8 vf = *(const bf16x8*)(&Vs[cur][offV[dt]]);
          o[0][dt] = __builtin_amdgcn_mfma_f32_16x16x32_bf16(pf0, vf, o[0][dt], 0, 0, 0);
          o[1][dt] = __builtin_amdgcn_mfma_f32_16x16x32_bf16(pf1, vf, o[1][dt], 0, 0, 0);
        }
        lac[0] = __builtin_amdgcn_mfma_f32_16x16x32_bf16(pf0, ones, lac[0], 0, 0, 0);
        lac[1] = __builtin_amdgcn_mfma_f32_16x16x32_bf16(pf1, ones, lac[1], 0, 0, 0);
      } else {
#pragma unroll
        for (int dt = 0; dt < 8; dt++) {
          bf16x8 vf = *(const bf16x8*)(&Vs[cur][offV[dt]]);
          o[1][dt] = __builtin_amdgcn_mfma_f32_16x16x32_bf16(pf1, vf, o[1][dt], 0, 0, 0);
        }
        lac[1] = __builtin_amdgcn_mfma_f32_16x16x32_bf16(pf1, ones, lac[1], 0, 0, 0);
      }
      __builtin_amdgcn_s_setprio(0);
    }
    cur ^= 1;
  }

#pragma unroll
  for (int m = 0; m < 2; m++) {
    const int Tm = m ? T1 : T0;
#pragma unroll
    for (int r = 0; r < 4; r++) {
      const float inv_l = 1.0f / lac[m][r];
      const size_t rowoff = (size_t)(Tm + quad * 4 + r) * HID + h * HD;
#pragma unroll
      for (int dt = 0; dt < 8; dt++)
        attn[rowoff + dt * 16 + lrow] = (__bf16)(o[m][dt][r] * inv_l);
    }
  }
}

// ---------- launch ----------
extern "C" void kernel_launch(void* const* d_in, const int* in_sizes, int n_in,
                              void* d_out, int out_size, void* d_ws, size_t ws_size,
                              hipStream_t stream) {
  const float* hs = (const float*)d_in[0];
  const int* pos = (const int*)d_in[2];
  const float* Wq = (const float*)d_in[3];
  const float* bq = (const float*)d_in[4];
  const float* Wk = (const float*)d_in[5];
  const float* bk = (const float*)d_in[6];
  const float* Wv = (const float*)d_in[7];
  const float* bv = (const float*)d_in[8];
  const float* Wo = (const float*)d_in[9];
  const float* bo = (const float*)d_in[10];
  float* out = (float*)d_out;
  char* ws = (char*)d_ws;
  char* oc = (char*)d_out;

  // ws layout (48 MB total):
  __bf16* bHS   = (__bf16*)(ws + 0);                   // 16 MB; reused as bAttn
  __bf16* bWT   = (__bf16*)(ws + ((size_t)16 << 20));  // 32 MB transposed weights
  __bf16* bAttn = bHS;
  // d_out scratch (28 MB of its 32 MB; final GEMM overwrites everything):
  __bf16* bQ   = (__bf16*)(oc + 0);                    // 16 MB [2048][4096]
  __bf16* bKV  = (__bf16*)(oc + ((size_t)16 << 20));   // 8 MB  [2048][2048] = K|V
  __bf16* bVt  = (__bf16*)(oc + ((size_t)24 << 20));   // 4 MB  [1024][2048]
  float*  bKVb = (float*)(oc + ((size_t)28 << 20));    // 8 KB concat bias

  dim3 tb(32, 8);

  // 1. hidden -> bf16
  cast_bf16<<<8192, 256, 0, stream>>>(hs, bHS, (S_LEN * HID) / 4);
  // 2. Wq^T ; Q = hs @ Wq + bq  (bf16 out into d_out scratch)
  transpose_cast<float><<<dim3(128, 128), tb, 0, stream>>>(Wq, bWT, 4096, 4096);
  gemm_bt<__bf16><<<dim3(32, 16), 256, 0, stream>>>(bHS, bWT, bq, bQ, 2048, 4096, 4096);
  // 3. [Wk|Wv]^T fused ; KV = hs @ [Wk|Wv] + [bk|bv]
  transpose_cast<float><<<dim3(32, 128), tb, 0, stream>>>(Wk, bWT, 1024, 4096);
  transpose_cast<float><<<dim3(32, 128), tb, 0, stream>>>(Wv, bWT + (size_t)1024 * 4096, 1024, 4096);
  concat_bias<<<8, 256, 0, stream>>>(bk, bv, bKVb);
  gemm_bt<__bf16><<<dim3(16, 16), 256, 0, stream>>>(bHS, bWT, bKVb, bKV, 2048, 2048, 4096);
  // 4. RoPE in-place on bQ and K-part of bKV ; V -> V^T
  rope_inplace<<<dim3(10, 2048), 256, 0, stream>>>(bQ, bKV, pos);
  transpose_cast<__bf16><<<dim3(32, 64), tb, 0, stream>>>(bKV + 1024, bVt, 2048, 2048);
  // 5. flash attention -> bAttn (reuses bHS region)
  flash_attn<<<512, 256, 0, stream>>>(bQ, bKV, bVt, bAttn, 2048);
  // 6. Wo^T ; out = attn @ Wo + bo (fp32, overwrites all d_out scratch)
  transpose_cast<float><<<dim3(128, 128), tb, 0, stream>>>(Wo, bWT, 4096, 4096);
  gemm_bt<float><<<dim3(32, 16), 256, 0, stream>>>(bAttn, bWT, bo, out, 2048, 4096, 4096);
}

// Round 4
// 565.685 us; speedup vs baseline: 1.0990x; 1.0175x over previous
//
#include <hip/hip_runtime.h>
#include <hip/hip_bf16.h>
#include <math.h>

// ---------- types ----------
typedef __bf16 bf16x8 __attribute__((ext_vector_type(8)));
typedef __bf16 bf16x4 __attribute__((ext_vector_type(4)));
typedef float  f32x4  __attribute__((ext_vector_type(4)));
typedef unsigned int u32;

#define S_LEN 2048
#define HID   4096
#define NH    32
#define NKV   8
#define HD    128

// async global->LDS 16B: per-lane global addr, LDS dest = wave-uniform base + lane*16
__device__ inline void gld_lds16(const __bf16* g, __bf16* l) {
  __builtin_amdgcn_global_load_lds((const __attribute__((address_space(1))) u32*)g,
                                   (__attribute__((address_space(3))) u32*)l,
                                   16, 0, 0);
}

// ---------- fp32 -> bf16 cast (vectorized) ----------
__global__ void cast_bf16(const float* __restrict__ in, __bf16* __restrict__ out, int n4) {
  int i = blockIdx.x * blockDim.x + threadIdx.x;
  if (i < n4) {
    float4 v = ((const float4*)in)[i];
    bf16x4 o;
    o[0] = (__bf16)v.x; o[1] = (__bf16)v.y; o[2] = (__bf16)v.z; o[3] = (__bf16)v.w;
    ((bf16x4*)out)[i] = o;
  }
}

// ---------- [R][C] (row stride ldi) -> bf16 [C][R] (row stride ldo) ----------
template <typename T>
__global__ void transpose_cast(const T* __restrict__ in, __bf16* __restrict__ out,
                               int ldi, int ldo) {
  __shared__ float tile[32][33];
  const int c0 = blockIdx.x * 32, r0 = blockIdx.y * 32;
  const int tx = threadIdx.x, ty = threadIdx.y;
  for (int j = 0; j < 32; j += 8)
    tile[ty + j][tx] = (float)in[(size_t)(r0 + ty + j) * ldi + c0 + tx];
  __syncthreads();
  for (int j = 0; j < 32; j += 8)
    out[(size_t)(c0 + ty + j) * ldo + r0 + tx] = (__bf16)tile[tx][ty + j];
}

__global__ void concat_bias(const float* __restrict__ bk, const float* __restrict__ bv,
                            float* __restrict__ out) {
  int i = blockIdx.x * blockDim.x + threadIdx.x;
  if (i < 2048) out[i] = (i < 1024) ? bk[i] : bv[i - 1024];
}

// ---------- GEMM: C[M][N] = A[M][K]bf16 @ Bt[N][K]bf16^T + bias[N] ----------
// 128x128 tile, BK=64, 4 waves each 64x64. Staging chunk c (0..1023): row=c>>3,
// kc=((c&7)+row)&7 (rotation keeps 8-lane/128B global coalescing AND bank-balanced
// ds_read_b128 fragment reads). LDS linear in c.
template <typename CT>
__global__ __launch_bounds__(256) void gemm_bt(const __bf16* __restrict__ A,
                                               const __bf16* __restrict__ Bt,
                                               const float* __restrict__ bias,
                                               CT* __restrict__ C,
                                               int M, int N, int K) {
  __shared__ __bf16 As[128 * 64];
  __shared__ __bf16 Bs[128 * 64];
  const int tid  = threadIdx.x;
  const int lane = tid & 63;
  const int lrow = lane & 15, quad = lane >> 4;
  const int wave = tid >> 6;
  const int wm = (wave & 1) * 64, wn = (wave >> 1) * 64;
  const int m0 = blockIdx.y * 128, n0 = blockIdx.x * 128;

  f32x4 acc[4][4] = {};

  // staging: 4 chunks per thread per matrix
  const __bf16* aP[4];
  const __bf16* bP[4];
  __bf16* aL[4];
  __bf16* bL[4];
#pragma unroll
  for (int s = 0; s < 4; s++) {
    const int c = tid + 256 * s;
    const int row = c >> 3;
    const int kc = ((c & 7) + row) & 7;
    aP[s] = A + (size_t)(m0 + row) * K + kc * 8;
    bP[s] = Bt + (size_t)(n0 + row) * K + kc * 8;
    aL[s] = As + c * 8;
    bL[s] = Bs + c * 8;
  }

  // fragment LDS element offsets (loop-invariant): chunk = r*8 + ((kc - r)&7)
  int offA[2][4], offB[2][4];
#pragma unroll
  for (int h = 0; h < 2; h++)
#pragma unroll
    for (int t = 0; t < 4; t++) {
      const int ra = wm + t * 16 + lrow;
      const int rb = wn + t * 16 + lrow;
      offA[h][t] = (ra * 8 + ((h * 4 + quad - ra) & 7)) * 8;
      offB[h][t] = (rb * 8 + ((h * 4 + quad - rb) & 7)) * 8;
    }

  for (int k0 = 0; k0 < K; k0 += 64) {
    __syncthreads();
#pragma unroll
    for (int s = 0; s < 4; s++) {
      gld_lds16(aP[s] + k0, aL[s]);
      gld_lds16(bP[s] + k0, bL[s]);
    }
    __syncthreads();

#pragma unroll
    for (int h = 0; h < 2; h++) {
      bf16x8 af[4], bfr[4];
#pragma unroll
      for (int t = 0; t < 4; t++) {
        af[t]  = *(const bf16x8*)(As + offA[h][t]);
        bfr[t] = *(const bf16x8*)(Bs + offB[h][t]);
      }
#pragma unroll
      for (int i = 0; i < 4; i++)
#pragma unroll
        for (int j = 0; j < 4; j++)
          acc[i][j] = __builtin_amdgcn_mfma_f32_16x16x32_bf16(af[i], bfr[j], acc[i][j], 0, 0, 0);
    }
  }

#pragma unroll
  for (int i = 0; i < 4; i++) {
    const int row = m0 + wm + i * 16 + quad * 4;
#pragma unroll
    for (int j = 0; j < 4; j++) {
      const int col = n0 + wn + j * 16 + lrow;
      const float b = bias[col];
#pragma unroll
      for (int r = 0; r < 4; r++)
        C[(size_t)(row + r) * N + col] = (CT)(acc[i][j][r] + b);
    }
  }
}

// ---------- RoPE in-place on bf16: Q [S][4096], KV [S][2048] (K = cols 0..1023) ----------
__global__ void rope_inplace(__bf16* __restrict__ Q, __bf16* __restrict__ KV,
                             const int* __restrict__ pos_ids) {
  const int s = blockIdx.y;
  const int t = blockIdx.x * blockDim.x + threadIdx.x;  // 0..2559
  const int h = t >> 6, j = t & 63;
  const float pos = (float)pos_ids[s];
  const float inv_freq = __builtin_exp2f((float)j * -0.2076205059304601f);
  const float ang = pos * inv_freq;
  float sn, cs;
  sincosf(ang, &sn, &cs);
  if (h < NH) {
    __bf16* p = Q + (size_t)s * HID + h * HD + j;
    const float x0 = (float)p[0], x1 = (float)p[64];
    p[0]  = (__bf16)(x0 * cs - x1 * sn);
    p[64] = (__bf16)(x1 * cs + x0 * sn);
  } else {
    const int hk = h - NH;
    __bf16* p = KV + (size_t)s * 2048 + hk * HD + j;
    const float x0 = (float)p[0], x1 = (float)p[64];
    p[0]  = (__bf16)(x0 * cs - x1 * sn);
    p[64] = (__bf16)(x1 * cs + x0 * sn);
  }
}

// ---------- flash attention v7 ----------
// Exactly the v4 structure (straight-line K-loop body -- branching inside the loop
// was proven -10% in v6: splits basic blocks, blocks ds_read hoisting, VGPR 112->96).
// ONLY change vs v4: the V bank rotation (isolated-proven in v5/v6 counters:
// conflicts 5.01M -> 2.73M):
//   stage: d=c>>2, vcb=((c&3)-(d>>1))&3 ; read rot (quad+(d>>1))&3
//   -> per-wave bank-group g = 4(lrow&1)+((quad+(lrow>>1))&3) uniform over 8 groups.
// No online max (scores bounded); row-sum via MFMA vs ones; no cross-lane ops.
// Balanced grid: blocks i and i+256 have complementary lengths.
__global__ __launch_bounds__(256) void flash_attn(const __bf16* __restrict__ Qb,
                                                  const __bf16* __restrict__ Kb,
                                                  const __bf16* __restrict__ Vt,
                                                  __bf16* __restrict__ attn, int ldk) {
  __shared__ __bf16 Ks[2][32 * 128];
  __shared__ __bf16 Vs[2][128 * 32];
  __shared__ __bf16 Plds[4][2][16][40];
  const int tid  = threadIdx.x;
  const int wave = tid >> 6;
  const int lane = tid & 63;
  const int lrow = lane & 15, quad = lane >> 4;

  const int c = blockIdx.x & 255, p = blockIdx.x >> 8;
  const int h = c >> 3;
  const int xh = c & 7;
  const int xx = p ? xh : 15 - xh;
  const int bq0 = xx * 128;
  const int kvh = h >> 2;
  const int T0 = bq0 + wave * 16;
  const int T1 = T0 + 64;
  const int kend = bq0 + 128;

  // staging chunk decode (2 K-chunks + 2 V-chunks per thread), rotated mappings
  const __bf16* kg[2];
  const __bf16* vg[2];
  int kL[2], vL[2];
#pragma unroll
  for (int s = 0; s < 2; s++) {
    const int ck = tid + 256 * s;
    const int key = ck >> 4, kcb = ((ck & 15) + key) & 15;
    kg[s] = Kb + (size_t)key * ldk + kvh * HD + kcb * 8;
    kL[s] = ck * 8;
    const int d = ck >> 2, vcb = ((ck & 3) - (d >> 1)) & 3;
    vg[s] = Vt + (size_t)(kvh * HD + d) * S_LEN + vcb * 8;
    vL[s] = ck * 8;
  }

  // fragment offsets (loop-invariant)
  // K: chunk = key*16 + ((cb - key)&15), cb = kc*4+quad ; kf0 key=lrow, kf1 key=lrow+16
  int offK0[4], offK1[4], offV[8];
#pragma unroll
  for (int kc = 0; kc < 4; kc++) {
    const int rot = (kc * 4 + quad - lrow) & 15;
    offK0[kc] = (lrow * 16 + rot) * 8;
    offK1[kc] = ((lrow + 16) * 16 + rot) * 8;
  }
  // V: chunk = d*4 + ((cb + (d>>1))&3), cb = quad ; d = dt*16 + lrow
#pragma unroll
  for (int dt = 0; dt < 8; dt++) {
    const int d = dt * 16 + lrow;
    offV[dt] = (d * 4 + ((quad + (d >> 1)) & 3)) * 8;
  }

  // Q fragments (held in regs for whole kernel)
  bf16x8 qf[2][4];
#pragma unroll
  for (int m = 0; m < 2; m++) {
    const __bf16* qbase = Qb + (size_t)(T0 + m * 64 + lrow) * HID + h * HD + quad * 8;
#pragma unroll
    for (int kc = 0; kc < 4; kc++) qf[m][kc] = *(const bf16x8*)(qbase + kc * 32);
  }

  f32x4 o[2][8] = {};
  f32x4 lac[2] = {};
  bf16x8 ones;
#pragma unroll
  for (int j = 0; j < 8; j++) ones[j] = (__bf16)1.0f;

  const float cs = 0.08838834764831845f * 1.44269504088896f;  // 1/sqrt(128)*log2(e)

  // preload tile kb=0 into buffer 0
#pragma unroll
  for (int s = 0; s < 2; s++) {
    gld_lds16(kg[s], &Ks[0][0] + kL[s]);
    gld_lds16(vg[s], &Vs[0][0] + vL[s]);
  }

  int cur = 0;
  for (int kb = 0; kb < kend; kb += 32) {
    __syncthreads();  // drains outstanding gld_lds (vmcnt) then barrier
    if (kb + 32 < kend) {
      const int nxt = cur ^ 1;
#pragma unroll
      for (int s = 0; s < 2; s++) {
        gld_lds16(kg[s] + (size_t)(kb + 32) * ldk, &Ks[nxt][0] + kL[s]);
        gld_lds16(vg[s] + (kb + 32), &Vs[nxt][0] + vL[s]);
      }
    }

    // K fragments from LDS (shared by both m-tiles)
    bf16x8 kf0[4], kf1[4];
#pragma unroll
    for (int kc = 0; kc < 4; kc++) {
      kf0[kc] = *(const bf16x8*)(&Ks[cur][offK0[kc]]);
      kf1[kc] = *(const bf16x8*)(&Ks[cur][offK1[kc]]);
    }
    f32x4 s[2][2] = {};
#pragma unroll
    for (int kc = 0; kc < 4; kc++) {
      s[0][0] = __builtin_amdgcn_mfma_f32_16x16x32_bf16(qf[0][kc], kf0[kc], s[0][0], 0, 0, 0);
      s[0][1] = __builtin_amdgcn_mfma_f32_16x16x32_bf16(qf[0][kc], kf1[kc], s[0][1], 0, 0, 0);
      s[1][0] = __builtin_amdgcn_mfma_f32_16x16x32_bf16(qf[1][kc], kf0[kc], s[1][0], 0, 0, 0);
      s[1][1] = __builtin_amdgcn_mfma_f32_16x16x32_bf16(qf[1][kc], kf1[kc], s[1][1], 0, 0, 0);
    }
    // exp2 (no max-sub) + causal mask, C-layout -> LDS
#pragma unroll
    for (int m = 0; m < 2; m++) {
      const int Tm = m ? T1 : T0;
#pragma unroll
      for (int n = 0; n < 2; n++) {
        const int col = kb + n * 16 + lrow;
#pragma unroll
        for (int r = 0; r < 4; r++) {
          const int row = Tm + quad * 4 + r;
          const float pv = (col <= row) ? __builtin_exp2f(s[m][n][r] * cs) : 0.0f;
          Plds[wave][m][quad * 4 + r][n * 16 + lrow] = (__bf16)pv;
        }
      }
    }
    // A-layout fragments (per-wave slice; same-wave DS ordering, no barrier)
    bf16x8 pf0 = *(const bf16x8*)(&Plds[wave][0][lrow][quad * 8]);
    bf16x8 pf1 = *(const bf16x8*)(&Plds[wave][1][lrow][quad * 8]);
#pragma unroll
    for (int dt = 0; dt < 8; dt++) {
      bf16x8 vf = *(const bf16x8*)(&Vs[cur][offV[dt]]);
      o[0][dt] = __builtin_amdgcn_mfma_f32_16x16x32_bf16(pf0, vf, o[0][dt], 0, 0, 0);
      o[1][dt] = __builtin_amdgcn_mfma_f32_16x16x32_bf16(pf1, vf, o[1][dt], 0, 0, 0);
    }
    lac[0] = __builtin_amdgcn_mfma_f32_16x16x32_bf16(pf0, ones, lac[0], 0, 0, 0);
    lac[1] = __builtin_amdgcn_mfma_f32_16x16x32_bf16(pf1, ones, lac[1], 0, 0, 0);
    cur ^= 1;
  }

#pragma unroll
  for (int m = 0; m < 2; m++) {
    const int Tm = m ? T1 : T0;
#pragma unroll
    for (int r = 0; r < 4; r++) {
      const float inv_l = 1.0f / lac[m][r];
      const size_t rowoff = (size_t)(Tm + quad * 4 + r) * HID + h * HD;
#pragma unroll
      for (int dt = 0; dt < 8; dt++)
        attn[rowoff + dt * 16 + lrow] = (__bf16)(o[m][dt][r] * inv_l);
    }
  }
}

// ---------- launch ----------
extern "C" void kernel_launch(void* const* d_in, const int* in_sizes, int n_in,
                              void* d_out, int out_size, void* d_ws, size_t ws_size,
                              hipStream_t stream) {
  const float* hs = (const float*)d_in[0];
  const int* pos = (const int*)d_in[2];
  const float* Wq = (const float*)d_in[3];
  const float* bq = (const float*)d_in[4];
  const float* Wk = (const float*)d_in[5];
  const float* bk = (const float*)d_in[6];
  const float* Wv = (const float*)d_in[7];
  const float* bv = (const float*)d_in[8];
  const float* Wo = (const float*)d_in[9];
  const float* bo = (const float*)d_in[10];
  float* out = (float*)d_out;
  char* ws = (char*)d_ws;
  char* oc = (char*)d_out;

  // ws layout (48 MB total):
  __bf16* bHS   = (__bf16*)(ws + 0);                   // 16 MB; reused as bAttn
  __bf16* bWT   = (__bf16*)(ws + ((size_t)16 << 20));  // 32 MB transposed weights
  __bf16* bAttn = bHS;
  // d_out scratch (28 MB of its 32 MB; final GEMM overwrites everything):
  __bf16* bQ   = (__bf16*)(oc + 0);                    // 16 MB [2048][4096]
  __bf16* bKV  = (__bf16*)(oc + ((size_t)16 << 20));   // 8 MB  [2048][2048] = K|V
  __bf16* bVt  = (__bf16*)(oc + ((size_t)24 << 20));   // 4 MB  [1024][2048]
  float*  bKVb = (float*)(oc + ((size_t)28 << 20));    // 8 KB concat bias

  dim3 tb(32, 8);

  // 1. hidden -> bf16
  cast_bf16<<<8192, 256, 0, stream>>>(hs, bHS, (S_LEN * HID) / 4);
  // 2. Wq^T ; Q = hs @ Wq + bq  (bf16 out into d_out scratch)
  transpose_cast<float><<<dim3(128, 128), tb, 0, stream>>>(Wq, bWT, 4096, 4096);
  gemm_bt<__bf16><<<dim3(32, 16), 256, 0, stream>>>(bHS, bWT, bq, bQ, 2048, 4096, 4096);
  // 3. [Wk|Wv]^T fused ; KV = hs @ [Wk|Wv] + [bk|bv]
  transpose_cast<float><<<dim3(32, 128), tb, 0, stream>>>(Wk, bWT, 1024, 4096);
  transpose_cast<float><<<dim3(32, 128), tb, 0, stream>>>(Wv, bWT + (size_t)1024 * 4096, 1024, 4096);
  concat_bias<<<8, 256, 0, stream>>>(bk, bv, bKVb);
  gemm_bt<__bf16><<<dim3(16, 16), 256, 0, stream>>>(bHS, bWT, bKVb, bKV, 2048, 2048, 4096);
  // 4. RoPE in-place on bQ and K-part of bKV ; V -> V^T
  rope_inplace<<<dim3(10, 2048), 256, 0, stream>>>(bQ, bKV, pos);
  transpose_cast<__bf16><<<dim3(32, 64), tb, 0, stream>>>(bKV + 1024, bVt, 2048, 2048);
  // 5. flash attention -> bAttn (reuses bHS region)
  flash_attn<<<512, 256, 0, stream>>>(bQ, bKV, bVt, bAttn, 2048);
  // 6. Wo^T ; out = attn @ Wo + bo (fp32, overwrites all d_out scratch)
  transpose_cast<float><<<dim3(128, 128), tb, 0, stream>>>(Wo, bWT, 4096, 4096);
  gemm_bt<float><<<dim3(32, 16), 256, 0, stream>>>(bAttn, bWT, bo, out, 2048, 4096, 4096);
}

// Round 6
// 559.314 us; speedup vs baseline: 1.1115x; 1.0114x over previous
//
#include <hip/hip_runtime.h>
#include <hip/hip_bf16.h>
#include <math.h>

// ---------- types ----------
typedef __bf16 bf16x8 __attribute__((ext_vector_type(8)));
typedef __bf16 bf16x4 __attribute__((ext_vector_type(4)));
typedef float  f32x4  __attribute__((ext_vector_type(4)));
typedef unsigned int u32;

#define S_LEN 2048
#define HID   4096
#define NH    32
#define NKV   8
#define HD    128

// async global->LDS 16B: per-lane global addr, LDS dest = wave-uniform base + lane*16
__device__ inline void gld_lds16(const __bf16* g, __bf16* l) {
  __builtin_amdgcn_global_load_lds((const __attribute__((address_space(1))) u32*)g,
                                   (__attribute__((address_space(3))) u32*)l,
                                   16, 0, 0);
}

// ---------- fp32 -> bf16 cast (vectorized) ----------
__global__ void cast_bf16(const float* __restrict__ in, __bf16* __restrict__ out, int n4) {
  int i = blockIdx.x * blockDim.x + threadIdx.x;
  if (i < n4) {
    float4 v = ((const float4*)in)[i];
    bf16x4 o;
    o[0] = (__bf16)v.x; o[1] = (__bf16)v.y; o[2] = (__bf16)v.z; o[3] = (__bf16)v.w;
    ((bf16x4*)out)[i] = o;
  }
}

// ---------- [R][C] (row stride ldi) -> bf16 [C][R] (row stride ldo) ----------
template <typename T>
__global__ void transpose_cast(const T* __restrict__ in, __bf16* __restrict__ out,
                               int ldi, int ldo) {
  __shared__ float tile[32][33];
  const int c0 = blockIdx.x * 32, r0 = blockIdx.y * 32;
  const int tx = threadIdx.x, ty = threadIdx.y;
  for (int j = 0; j < 32; j += 8)
    tile[ty + j][tx] = (float)in[(size_t)(r0 + ty + j) * ldi + c0 + tx];
  __syncthreads();
  for (int j = 0; j < 32; j += 8)
    out[(size_t)(c0 + ty + j) * ldo + r0 + tx] = (__bf16)tile[tx][ty + j];
}

// ---------- V^T builder with key-column permutation within each 32-key block ----------
// slot = ((k>>2)&3)*8 + ((k>>4)&1)*4 + (k&3)  (tau^-1), so that flash's PV k-slot
// (quad*8 + 4n + r) holds key (quad*4 + r + 16n) -- matching the swapped-QK output
// register layout with ZERO cross-lane data movement.
__global__ void transpose_cast_vperm(const __bf16* __restrict__ in, __bf16* __restrict__ out,
                                     int ldi, int ldo) {
  __shared__ float tile[32][33];
  const int c0 = blockIdx.x * 32, r0 = blockIdx.y * 32;
  const int tx = threadIdx.x, ty = threadIdx.y;
  for (int j = 0; j < 32; j += 8)
    tile[ty + j][tx] = (float)in[(size_t)(r0 + ty + j) * ldi + c0 + tx];
  __syncthreads();
  const int sx = ((tx >> 2) & 3) * 8 + ((tx >> 4) & 1) * 4 + (tx & 3);
  for (int j = 0; j < 32; j += 8)
    out[(size_t)(c0 + ty + j) * ldo + r0 + sx] = (__bf16)tile[tx][ty + j];
}

__global__ void concat_bias(const float* __restrict__ bk, const float* __restrict__ bv,
                            float* __restrict__ out) {
  int i = blockIdx.x * blockDim.x + threadIdx.x;
  if (i < 2048) out[i] = (i < 1024) ? bk[i] : bv[i - 1024];
}

// ---------- GEMM: C[M][N] = A[M][K]bf16 @ Bt[N][K]bf16^T + bias[N] ----------
// 128x128 tile, BK=64, 4 waves each 64x64. Staging chunk c (0..1023): row=c>>3,
// kc=((c&7)+row)&7 (rotation keeps 8-lane/128B global coalescing AND bank-balanced
// ds_read_b128 fragment reads). LDS linear in c.
template <typename CT>
__global__ __launch_bounds__(256) void gemm_bt(const __bf16* __restrict__ A,
                                               const __bf16* __restrict__ Bt,
                                               const float* __restrict__ bias,
                                               CT* __restrict__ C,
                                               int M, int N, int K) {
  __shared__ __bf16 As[128 * 64];
  __shared__ __bf16 Bs[128 * 64];
  const int tid  = threadIdx.x;
  const int lane = tid & 63;
  const int lrow = lane & 15, quad = lane >> 4;
  const int wave = tid >> 6;
  const int wm = (wave & 1) * 64, wn = (wave >> 1) * 64;
  const int m0 = blockIdx.y * 128, n0 = blockIdx.x * 128;

  f32x4 acc[4][4] = {};

  // staging: 4 chunks per thread per matrix
  const __bf16* aP[4];
  const __bf16* bP[4];
  __bf16* aL[4];
  __bf16* bL[4];
#pragma unroll
  for (int s = 0; s < 4; s++) {
    const int c = tid + 256 * s;
    const int row = c >> 3;
    const int kc = ((c & 7) + row) & 7;
    aP[s] = A + (size_t)(m0 + row) * K + kc * 8;
    bP[s] = Bt + (size_t)(n0 + row) * K + kc * 8;
    aL[s] = As + c * 8;
    bL[s] = Bs + c * 8;
  }

  // fragment LDS element offsets (loop-invariant): chunk = r*8 + ((kc - r)&7)
  int offA[2][4], offB[2][4];
#pragma unroll
  for (int h = 0; h < 2; h++)
#pragma unroll
    for (int t = 0; t < 4; t++) {
      const int ra = wm + t * 16 + lrow;
      const int rb = wn + t * 16 + lrow;
      offA[h][t] = (ra * 8 + ((h * 4 + quad - ra) & 7)) * 8;
      offB[h][t] = (rb * 8 + ((h * 4 + quad - rb) & 7)) * 8;
    }

  for (int k0 = 0; k0 < K; k0 += 64) {
    __syncthreads();
#pragma unroll
    for (int s = 0; s < 4; s++) {
      gld_lds16(aP[s] + k0, aL[s]);
      gld_lds16(bP[s] + k0, bL[s]);
    }
    __syncthreads();

#pragma unroll
    for (int h = 0; h < 2; h++) {
      bf16x8 af[4], bfr[4];
#pragma unroll
      for (int t = 0; t < 4; t++) {
        af[t]  = *(const bf16x8*)(As + offA[h][t]);
        bfr[t] = *(const bf16x8*)(Bs + offB[h][t]);
      }
#pragma unroll
      for (int i = 0; i < 4; i++)
#pragma unroll
        for (int j = 0; j < 4; j++)
          acc[i][j] = __builtin_amdgcn_mfma_f32_16x16x32_bf16(af[i], bfr[j], acc[i][j], 0, 0, 0);
    }
  }

#pragma unroll
  for (int i = 0; i < 4; i++) {
    const int row = m0 + wm + i * 16 + quad * 4;
#pragma unroll
    for (int j = 0; j < 4; j++) {
      const int col = n0 + wn + j * 16 + lrow;
      const float b = bias[col];
#pragma unroll
      for (int r = 0; r < 4; r++)
        C[(size_t)(row + r) * N + col] = (CT)(acc[i][j][r] + b);
    }
  }
}

// ---------- RoPE in-place on bf16: Q [S][4096], KV [S][2048] (K = cols 0..1023) ----------
__global__ void rope_inplace(__bf16* __restrict__ Q, __bf16* __restrict__ KV,
                             const int* __restrict__ pos_ids) {
  const int s = blockIdx.y;
  const int t = blockIdx.x * blockDim.x + threadIdx.x;  // 0..2559
  const int h = t >> 6, j = t & 63;
  const float pos = (float)pos_ids[s];
  const float inv_freq = __builtin_exp2f((float)j * -0.2076205059304601f);
  const float ang = pos * inv_freq;
  float sn, cs;
  sincosf(ang, &sn, &cs);
  if (h < NH) {
    __bf16* p = Q + (size_t)s * HID + h * HD + j;
    const float x0 = (float)p[0], x1 = (float)p[64];
    p[0]  = (__bf16)(x0 * cs - x1 * sn);
    p[64] = (__bf16)(x1 * cs + x0 * sn);
  } else {
    const int hk = h - NH;
    __bf16* p = KV + (size_t)s * 2048 + hk * HD + j;
    const float x0 = (float)p[0], x1 = (float)p[64];
    p[0]  = (__bf16)(x0 * cs - x1 * sn);
    p[64] = (__bf16)(x1 * cs + x0 * sn);
  }
}

// ---------- flash attention v8 ----------
// v7 structure + swapped QK^T with in-register P (NO P LDS round-trip):
//  s = mfma(K, Q): lane holds S[key = kb + n*16 + quad*4 + r][query = Tm + lrow]
//  -> after exp2+mask, pack pf[m][n*4+r] in registers = PV A-fragment directly,
//  because Vt is built with key-columns permuted (transpose_cast_vperm) so PV's
//  k-slot (quad*8 + 4n + r) holds key (quad*4 + r + 16n). MFMA is permutation-
//  invariant when both operands use the same key ordering.
// DS instrs per wave-iter: 34 -> 16 (8 K-reads + 8 V-reads); Plds deleted (LDS 32KB).
// K staging/rotation, V staging/rotation (v7-proven), epilogue: unchanged.
__global__ __launch_bounds__(256) void flash_attn(const __bf16* __restrict__ Qb,
                                                  const __bf16* __restrict__ Kb,
                                                  const __bf16* __restrict__ Vt,
                                                  __bf16* __restrict__ attn, int ldk) {
  __shared__ __bf16 Ks[2][32 * 128];
  __shared__ __bf16 Vs[2][128 * 32];
  const int tid  = threadIdx.x;
  const int wave = tid >> 6;
  const int lane = tid & 63;
  const int lrow = lane & 15, quad = lane >> 4;

  const int c = blockIdx.x & 255, p = blockIdx.x >> 8;
  const int h = c >> 3;
  const int xh = c & 7;
  const int xx = p ? xh : 15 - xh;
  const int bq0 = xx * 128;
  const int kvh = h >> 2;
  const int T0 = bq0 + wave * 16;
  const int T1 = T0 + 64;
  const int kend = bq0 + 128;

  // staging chunk decode (2 K-chunks + 2 V-chunks per thread), rotated mappings
  const __bf16* kg[2];
  const __bf16* vg[2];
  int kL[2], vL[2];
#pragma unroll
  for (int s = 0; s < 2; s++) {
    const int ck = tid + 256 * s;
    const int key = ck >> 4, kcb = ((ck & 15) + key) & 15;
    kg[s] = Kb + (size_t)key * ldk + kvh * HD + kcb * 8;
    kL[s] = ck * 8;
    const int d = ck >> 2, vcb = ((ck & 3) - (d >> 1)) & 3;
    vg[s] = Vt + (size_t)(kvh * HD + d) * S_LEN + vcb * 8;
    vL[s] = ck * 8;
  }

  // fragment offsets (loop-invariant)
  // K: chunk = key*16 + ((cb - key)&15), cb = kc*4+quad ; kf0 key=lrow, kf1 key=lrow+16
  int offK0[4], offK1[4], offV[8];
#pragma unroll
  for (int kc = 0; kc < 4; kc++) {
    const int rot = (kc * 4 + quad - lrow) & 15;
    offK0[kc] = (lrow * 16 + rot) * 8;
    offK1[kc] = ((lrow + 16) * 16 + rot) * 8;
  }
  // V: chunk = d*4 + ((cb + (d>>1))&3), cb = quad ; d = dt*16 + lrow
#pragma unroll
  for (int dt = 0; dt < 8; dt++) {
    const int d = dt * 16 + lrow;
    offV[dt] = (d * 4 + ((quad + (d >> 1)) & 3)) * 8;
  }

  // Q fragments (held in regs for whole kernel)
  bf16x8 qf[2][4];
#pragma unroll
  for (int m = 0; m < 2; m++) {
    const __bf16* qbase = Qb + (size_t)(T0 + m * 64 + lrow) * HID + h * HD + quad * 8;
#pragma unroll
    for (int kc = 0; kc < 4; kc++) qf[m][kc] = *(const bf16x8*)(qbase + kc * 32);
  }

  f32x4 o[2][8] = {};
  f32x4 lac[2] = {};
  bf16x8 ones;
#pragma unroll
  for (int j = 0; j < 8; j++) ones[j] = (__bf16)1.0f;

  const float cs = 0.08838834764831845f * 1.44269504088896f;  // 1/sqrt(128)*log2(e)

  // preload tile kb=0 into buffer 0
#pragma unroll
  for (int s = 0; s < 2; s++) {
    gld_lds16(kg[s], &Ks[0][0] + kL[s]);
    gld_lds16(vg[s], &Vs[0][0] + vL[s]);
  }

  int cur = 0;
  for (int kb = 0; kb < kend; kb += 32) {
    __syncthreads();  // drains outstanding gld_lds (vmcnt) then barrier
    if (kb + 32 < kend) {
      const int nxt = cur ^ 1;
#pragma unroll
      for (int s = 0; s < 2; s++) {
        gld_lds16(kg[s] + (size_t)(kb + 32) * ldk, &Ks[nxt][0] + kL[s]);
        gld_lds16(vg[s] + (kb + 32), &Vs[nxt][0] + vL[s]);
      }
    }

    // K fragments from LDS (shared by both m-tiles)
    bf16x8 kf0[4], kf1[4];
#pragma unroll
    for (int kc = 0; kc < 4; kc++) {
      kf0[kc] = *(const bf16x8*)(&Ks[cur][offK0[kc]]);
      kf1[kc] = *(const bf16x8*)(&Ks[cur][offK1[kc]]);
    }
    // swapped QK^T: rows = keys, cols = queries
    f32x4 s[2][2] = {};
#pragma unroll
    for (int kc = 0; kc < 4; kc++) {
      s[0][0] = __builtin_amdgcn_mfma_f32_16x16x32_bf16(kf0[kc], qf[0][kc], s[0][0], 0, 0, 0);
      s[0][1] = __builtin_amdgcn_mfma_f32_16x16x32_bf16(kf1[kc], qf[0][kc], s[0][1], 0, 0, 0);
      s[1][0] = __builtin_amdgcn_mfma_f32_16x16x32_bf16(kf0[kc], qf[1][kc], s[1][0], 0, 0, 0);
      s[1][1] = __builtin_amdgcn_mfma_f32_16x16x32_bf16(kf1[kc], qf[1][kc], s[1][1], 0, 0, 0);
    }
    // exp2 (no max-sub) + causal mask, packed in-register into PV A-fragments
    bf16x8 pf[2];
#pragma unroll
    for (int m = 0; m < 2; m++) {
      const int qrow = (m ? T1 : T0) + lrow;
#pragma unroll
      for (int n = 0; n < 2; n++)
#pragma unroll
        for (int r = 0; r < 4; r++) {
          const int key = kb + n * 16 + quad * 4 + r;
          const float pv = (key <= qrow) ? __builtin_exp2f(s[m][n][r] * cs) : 0.0f;
          pf[m][n * 4 + r] = (__bf16)pv;
        }
    }
#pragma unroll
    for (int dt = 0; dt < 8; dt++) {
      bf16x8 vf = *(const bf16x8*)(&Vs[cur][offV[dt]]);
      o[0][dt] = __builtin_amdgcn_mfma_f32_16x16x32_bf16(pf[0], vf, o[0][dt], 0, 0, 0);
      o[1][dt] = __builtin_amdgcn_mfma_f32_16x16x32_bf16(pf[1], vf, o[1][dt], 0, 0, 0);
    }
    lac[0] = __builtin_amdgcn_mfma_f32_16x16x32_bf16(pf[0], ones, lac[0], 0, 0, 0);
    lac[1] = __builtin_amdgcn_mfma_f32_16x16x32_bf16(pf[1], ones, lac[1], 0, 0, 0);
    cur ^= 1;
  }

#pragma unroll
  for (int m = 0; m < 2; m++) {
    const int Tm = m ? T1 : T0;
#pragma unroll
    for (int r = 0; r < 4; r++) {
      const float inv_l = 1.0f / lac[m][r];
      const size_t rowoff = (size_t)(Tm + quad * 4 + r) * HID + h * HD;
#pragma unroll
      for (int dt = 0; dt < 8; dt++)
        attn[rowoff + dt * 16 + lrow] = (__bf16)(o[m][dt][r] * inv_l);
    }
  }
}

// ---------- launch ----------
extern "C" void kernel_launch(void* const* d_in, const int* in_sizes, int n_in,
                              void* d_out, int out_size, void* d_ws, size_t ws_size,
                              hipStream_t stream) {
  const float* hs = (const float*)d_in[0];
  const int* pos = (const int*)d_in[2];
  const float* Wq = (const float*)d_in[3];
  const float* bq = (const float*)d_in[4];
  const float* Wk = (const float*)d_in[5];
  const float* bk = (const float*)d_in[6];
  const float* Wv = (const float*)d_in[7];
  const float* bv = (const float*)d_in[8];
  const float* Wo = (const float*)d_in[9];
  const float* bo = (const float*)d_in[10];
  float* out = (float*)d_out;
  char* ws = (char*)d_ws;
  char* oc = (char*)d_out;

  // ws layout (48 MB total):
  __bf16* bHS   = (__bf16*)(ws + 0);                   // 16 MB; reused as bAttn
  __bf16* bWT   = (__bf16*)(ws + ((size_t)16 << 20));  // 32 MB transposed weights
  __bf16* bAttn = bHS;
  // d_out scratch (28 MB of its 32 MB; final GEMM overwrites everything):
  __bf16* bQ   = (__bf16*)(oc + 0);                    // 16 MB [2048][4096]
  __bf16* bKV  = (__bf16*)(oc + ((size_t)16 << 20));   // 8 MB  [2048][2048] = K|V
  __bf16* bVt  = (__bf16*)(oc + ((size_t)24 << 20));   // 4 MB  [1024][2048]
  float*  bKVb = (float*)(oc + ((size_t)28 << 20));    // 8 KB concat bias

  dim3 tb(32, 8);

  // 1. hidden -> bf16
  cast_bf16<<<8192, 256, 0, stream>>>(hs, bHS, (S_LEN * HID) / 4);
  // 2. Wq^T ; Q = hs @ Wq + bq  (bf16 out into d_out scratch)
  transpose_cast<float><<<dim3(128, 128), tb, 0, stream>>>(Wq, bWT, 4096, 4096);
  gemm_bt<__bf16><<<dim3(32, 16), 256, 0, stream>>>(bHS, bWT, bq, bQ, 2048, 4096, 4096);
  // 3. [Wk|Wv]^T fused ; KV = hs @ [Wk|Wv] + [bk|bv]
  transpose_cast<float><<<dim3(32, 128), tb, 0, stream>>>(Wk, bWT, 1024, 4096);
  transpose_cast<float><<<dim3(32, 128), tb, 0, stream>>>(Wv, bWT + (size_t)1024 * 4096, 1024, 4096);
  concat_bias<<<8, 256, 0, stream>>>(bk, bv, bKVb);
  gemm_bt<__bf16><<<dim3(16, 16), 256, 0, stream>>>(bHS, bWT, bKVb, bKV, 2048, 2048, 4096);
  // 4. RoPE in-place on bQ and K-part of bKV ; V -> V^T (key-permuted for flash v8)
  rope_inplace<<<dim3(10, 2048), 256, 0, stream>>>(bQ, bKV, pos);
  transpose_cast_vperm<<<dim3(32, 64), tb, 0, stream>>>(bKV + 1024, bVt, 2048, 2048);
  // 5. flash attention -> bAttn (reuses bHS region)
  flash_attn<<<512, 256, 0, stream>>>(bQ, bKV, bVt, bAttn, 2048);
  // 6. Wo^T ; out = attn @ Wo + bo (fp32, overwrites all d_out scratch)
  transpose_cast<float><<<dim3(128, 128), tb, 0, stream>>>(Wo, bWT, 4096, 4096);
  gemm_bt<float><<<dim3(32, 16), 256, 0, stream>>>(bAttn, bWT, bo, out, 2048, 4096, 4096);
}